// Round 1
// baseline (29247.906 us; speedup 1.0000x reference)
//
#include <hip/hip_runtime.h>

#define B_SZ 128
#define T_SZ 1024
#define NIN 128
#define NHID 512
#define NOUT 128

// d_out layout (float elements)
#define HID_OFF 0
#define OUT_OFF ((size_t)B_SZ * T_SZ * NHID)              // 67,108,864
#define HFIN_OFF (OUT_OFF + (size_t)B_SZ * T_SZ * NOUT)   // 83,886,080

// d_ws layout (bytes)
#define WS_CNT 0                 // 16 counters, stride 64B (4KB reserved, memset to 0)
#define WS_HBUF 4096             // h_0 staging [128][512] f32 = 256KB
#define WS_WCOMB (4096 + B_SZ * NHID * 4)        // 266240: W_comb [512][128] = 256KB
#define WS_BCOMB (WS_WCOMB + NHID * NIN * 4)     // 528384: b_comb [512] = 2KB

// ---------------------------------------------------------------------------
// Kernel A0: W_comb[j,c] = sum_k W_ih[j,k] * W_in[k,c]
//            b_comb[j]   = sum_k W_ih[j,k] * b_in[k] + b_ih[j] + b_hh[j]
// ---------------------------------------------------------------------------
__global__ __launch_bounds__(128) void wcomb_k(
    const float* __restrict__ Wih, const float* __restrict__ Win,
    const float* __restrict__ b_in, const float* __restrict__ b_ih,
    const float* __restrict__ b_hh, float* __restrict__ Wc,
    float* __restrict__ bc)
{
  const int j = blockIdx.x;   // 0..511
  const int c = threadIdx.x;  // 0..127
  const float* wr = Wih + (size_t)j * NHID;
  float acc = 0.f, bacc = 0.f;
#pragma unroll 8
  for (int k = 0; k < NHID; ++k) acc += wr[k] * Win[(size_t)k * NIN + c];
  for (int k = c; k < NHID; k += 128) bacc += wr[k] * b_in[k];
  Wc[(size_t)j * NIN + c] = acc;

  __shared__ float red[128];
  red[c] = bacc;
  __syncthreads();
#pragma unroll
  for (int s = 64; s > 0; s >>= 1) {
    if (c < s) red[c] += red[c + s];
    __syncthreads();
  }
  if (c == 0) bc[j] = red[0] + b_ih[j] + b_hh[j];
}

// ---------------------------------------------------------------------------
// Generic tiled fp32 GEMM: C[m,n] = sum_k A[m,k]*B[n,k] + bias[n]
// 64x64 tile, 256 threads, 4x4 register block, XOR-swizzled LDS.
// M and N multiples of 64, K multiple of 64.
// ---------------------------------------------------------------------------
__global__ __launch_bounds__(256) void gemm_abt(
    const float* __restrict__ A, const float* __restrict__ Bm,
    const float* __restrict__ bias, float* __restrict__ C,
    int lda, int ldb, int ldc, int K)
{
  __shared__ float As[64 * 64];
  __shared__ float Bs[64 * 64];
  const int t = threadIdx.x;
  const int tr = t >> 4, tc = t & 15;
  const float* Ab = A + (size_t)blockIdx.x * 64 * lda;
  const float* Bb = Bm + (size_t)blockIdx.y * 64 * ldb;
  float acc[4][4] = {};

  for (int k0 = 0; k0 < K; k0 += 64) {
#pragma unroll
    for (int s = 0; s < 4; ++s) {
      int idx = s * 256 + t;               // 0..1023
      int row = idx >> 4;                  // 0..63
      int kk = (idx & 15) << 2;            // 0..60
      float4 av = *(const float4*)(Ab + (size_t)row * lda + k0 + kk);
      float4 bv = *(const float4*)(Bb + (size_t)row * ldb + k0 + kk);
      int sw = kk ^ (((row >> 2) & 7) << 2);
      *(float4*)(&As[row * 64 + sw]) = av;
      *(float4*)(&Bs[row * 64 + sw]) = bv;
    }
    __syncthreads();
#pragma unroll
    for (int kk = 0; kk < 64; kk += 4) {
      float4 av[4], bv[4];
#pragma unroll
      for (int i = 0; i < 4; ++i) {
        av[i] = *(const float4*)(&As[(tr * 4 + i) * 64 + (kk ^ ((tr & 7) << 2))]);
        bv[i] = *(const float4*)(&Bs[(tc * 4 + i) * 64 + (kk ^ ((tc & 7) << 2))]);
      }
#pragma unroll
      for (int i = 0; i < 4; ++i)
#pragma unroll
        for (int jn = 0; jn < 4; ++jn) {
          acc[i][jn] += av[i].x * bv[jn].x;
          acc[i][jn] += av[i].y * bv[jn].y;
          acc[i][jn] += av[i].z * bv[jn].z;
          acc[i][jn] += av[i].w * bv[jn].w;
        }
    }
    __syncthreads();
  }

  const int m0 = blockIdx.x * 64 + tr * 4;
  const int n0 = blockIdx.y * 64 + tc * 4;
  float4 bb = *(const float4*)(bias + n0);
#pragma unroll
  for (int i = 0; i < 4; ++i) {
    float4 o;
    o.x = acc[i][0] + bb.x;
    o.y = acc[i][1] + bb.y;
    o.z = acc[i][2] + bb.z;
    o.w = acc[i][3] + bb.w;
    *(float4*)(C + (size_t)(m0 + i) * ldc + n0) = o;
  }
}

// ---------------------------------------------------------------------------
// Persistent scan kernel.
// Grid 256 = 16 rowgroups (8 batch rows) x 16 jgroups (32 outputs).
// Thread (j2 = t&15, ks = t>>4) holds W_hh[jg*32+j2*2 .. +1][ks*32 .. +31]
// in 64 VGPRs for the whole sequence. Partials reduced over ks via LDS.
// h_t for step t (t>0) is read from hid[b, t-1, :] (h slots written once).
// Cross-WG sync within a rowgroup: fence + monotonic counter.
// ---------------------------------------------------------------------------
__global__ __launch_bounds__(256, 1) void scan_k(
    const float* __restrict__ Whh, const float* __restrict__ h0,
    float* __restrict__ hid, float* __restrict__ hfin,
    float* __restrict__ hbuf, unsigned* __restrict__ cnt)
{
  const int bid = blockIdx.x;
  const int rowg = bid >> 4;      // 0..15
  const int jg = bid & 15;        // 0..15
  const int t = threadIdx.x;
  const int j2 = t & 15;          // 0..15 (pair of output cols)
  const int ks = t >> 4;          // 0..15 (k-chunk of 32)
  __shared__ float ps[16 * 256];  // [ks][output]

  // persistent W_hh block in registers
  float w0[32], w1[32];
  {
    const float* wp0 = Whh + (size_t)(jg * 32 + j2 * 2 + 0) * NHID + ks * 32;
    const float* wp1 = Whh + (size_t)(jg * 32 + j2 * 2 + 1) * NHID + ks * 32;
#pragma unroll
    for (int q = 0; q < 8; ++q) {
      float4 a = *(const float4*)(wp0 + q * 4);
      float4 b = *(const float4*)(wp1 + q * 4);
      w0[q * 4 + 0] = a.x; w0[q * 4 + 1] = a.y; w0[q * 4 + 2] = a.z; w0[q * 4 + 3] = a.w;
      w1[q * 4 + 0] = b.x; w1[q * 4 + 1] = b.y; w1[q * 4 + 2] = b.z; w1[q * 4 + 3] = b.w;
    }
  }

  // this thread's owned output element (for reduce/store phase)
  const int ro = t >> 5;              // 0..7
  const int jlo = t & 31;             // 0..31
  const int b_o = rowg * 8 + ro;      // batch row
  const int jcol = jg * 32 + jlo;     // hidden col
  unsigned* cptr = cnt + rowg * 16;   // 64B-strided counters

  // stage h_0 into hbuf (step-0 input for the whole rowgroup)
  hbuf[(size_t)b_o * NHID + jcol] = h0[(size_t)b_o * NHID + jcol];
  float hcur = h0[(size_t)b_o * NHID + jcol];  // running h for owned element
  __threadfence();
  __syncthreads();
  if (t == 0) __hip_atomic_fetch_add(cptr, 1u, __ATOMIC_RELAXED, __HIP_MEMORY_SCOPE_AGENT);

  const size_t rowpitch = (size_t)T_SZ * NHID;  // 524288 floats between batch rows of hid
  const float* hsrc0 = hbuf + (size_t)rowg * 8 * NHID + ks * 32;
  const float* hsrcN = hid + (size_t)rowg * 8 * rowpitch + ks * 32;

  float znext = hid[((size_t)b_o * T_SZ + 0) * NHID + jcol];

  for (int step = 0; step < T_SZ; ++step) {
    // --- wait for all 16 WGs of this rowgroup to finish step-1 ---
    const unsigned target = 16u * (unsigned)(step + 1);
    if (t < 64) {
      while (__hip_atomic_load(cptr, __ATOMIC_RELAXED, __HIP_MEMORY_SCOPE_AGENT) < target)
        __builtin_amdgcn_s_sleep(4);
    }
    __syncthreads();
    __builtin_amdgcn_fence(__ATOMIC_ACQUIRE, "agent");

    // --- partial matvec: accp[r][jj] = sum_{k in ks-chunk} W[j][k] h[b_r][k] ---
    const float* hb;
    size_t hpitch;
    if (step == 0) { hb = hsrc0; hpitch = NHID; }
    else           { hb = hsrcN + (size_t)(step - 1) * NHID; hpitch = rowpitch; }

    float accp[8][2];
#pragma unroll
    for (int r = 0; r < 8; ++r) {
      const float* hp = hb + (size_t)r * hpitch;
      float hv[32];
#pragma unroll
      for (int q = 0; q < 8; ++q) {
        float4 v = *(const float4*)(hp + q * 4);
        hv[q * 4 + 0] = v.x; hv[q * 4 + 1] = v.y;
        hv[q * 4 + 2] = v.z; hv[q * 4 + 3] = v.w;
      }
      float a0 = 0.f, a1 = 0.f;
#pragma unroll
      for (int c2 = 0; c2 < 32; ++c2) {
        a0 += w0[c2] * hv[c2];
        a1 += w1[c2] * hv[c2];
      }
      accp[r][0] = a0; accp[r][1] = a1;
    }
#pragma unroll
    for (int r = 0; r < 8; ++r) {
      float2 v; v.x = accp[r][0]; v.y = accp[r][1];
      *(float2*)(&ps[ks * 256 + r * 32 + j2 * 2]) = v;
    }
    __syncthreads();

    // --- reduce over 16 k-chunks; epilogue for owned element ---
    float sum = 0.f;
#pragma unroll
    for (int q = 0; q < 16; ++q) sum += ps[q * 256 + t];

    float zc = znext;
    if (step + 1 < T_SZ) znext = hid[((size_t)b_o * T_SZ + step + 1) * NHID + jcol];

    float hnew = fmaxf(zc + sum, 0.f);
    float hup = (1.0f - 0.1f) * hcur + 0.1f * hnew;
    hcur = hup;

    hid[((size_t)b_o * T_SZ + step) * NHID + jcol] = hup;   // hidden_list output (= next h input)
    if (step == T_SZ - 1) hfin[(size_t)b_o * NHID + jcol] = hup;

    // --- publish this step ---
    __threadfence();
    __syncthreads();  // also protects ps for next iteration
    if (t == 0) __hip_atomic_fetch_add(cptr, 1u, __ATOMIC_RELAXED, __HIP_MEMORY_SCOPE_AGENT);
  }
}

// ---------------------------------------------------------------------------
extern "C" void kernel_launch(void* const* d_in, const int* in_sizes, int n_in,
                              void* d_out, int out_size, void* d_ws, size_t ws_size,
                              hipStream_t stream) {
  const float* U    = (const float*)d_in[0];  // [128,1024,128]
  const float* h0   = (const float*)d_in[1];  // [128,512]
  const float* Win  = (const float*)d_in[2];  // [512,128]
  const float* b_in = (const float*)d_in[3];  // [512]
  const float* Wih  = (const float*)d_in[4];  // [512,512]
  const float* b_ih = (const float*)d_in[5];  // [512]
  const float* Whh  = (const float*)d_in[6];  // [512,512]
  const float* b_hh = (const float*)d_in[7];  // [512]
  const float* Wout = (const float*)d_in[8];  // [128,512]
  const float* bout = (const float*)d_in[9];  // [128]

  float* out_base = (float*)d_out;
  float* hid  = out_base + HID_OFF;   // [128,1024,512] : Z, then overwritten with h
  float* outl = out_base + OUT_OFF;   // [128,1024,128]
  float* hfin = out_base + HFIN_OFF;  // [128,512]

  unsigned* cnt = (unsigned*)d_ws;
  float* hbuf = (float*)((char*)d_ws + WS_HBUF);
  float* Wc   = (float*)((char*)d_ws + WS_WCOMB);
  float* bc   = (float*)((char*)d_ws + WS_BCOMB);

  // zero the sync counters (d_ws is poisoned before every launch)
  hipMemsetAsync(d_ws, 0, 4096, stream);

  // A0: combined input weight
  wcomb_k<<<512, 128, 0, stream>>>(Wih, Win, b_in, b_ih, b_hh, Wc, bc);

  // A1: Z = U @ Wc^T + bc   (M=131072, N=512, K=128) -> hid region
  gemm_abt<<<dim3(2048, 8), 256, 0, stream>>>(U, Wc, bc, hid, NIN, NIN, NHID, NIN);

  // Scan: in-place Z -> hidden_list, h_final
  scan_k<<<256, 256, 0, stream>>>(Whh, h0, hid, hfin, hbuf, cnt);

  // P3: out = hid @ Wout^T + bout   (M=131072, N=128, K=512)
  gemm_abt<<<dim3(2048, 2), 256, 0, stream>>>(hid, Wout, bout, outl, NHID, NHID, NOUT, NHID);
}